// Round 15
// baseline (528.442 us; speedup 1.0000x reference)
//
#include <hip/hip_runtime.h>
#include <math.h>

// Problem constants: x [B=16, C=64, H=256, W=256] fp32
#define BB   16
#define CC   64
#define HH_  256
#define WW_  256
#define HW   (HH_ * WW_)        // 65536
#define CHW  (CC * HW)          // 4194304
#define NPIX (BB * HW)          // 1048576

// K1 band geometry: small bands -> 4 blocks/CU, phases interleave across blocks.
#define BH   4                  // output rows per block
#define HALO 3                  // conv radius
#define PR   (BH + 2*HALO)      // 10 pooled rows in LDS
#define NBANDS (HH_ / BH)       // 64
#define NBLK (BB * NBANDS)      // 1024 blocks

// K2 streaming geometry
#define T4      (NPIX * CC / 4) // 16777216 float4 jobs
#define K2_BLK  2048
#define K2_THR  256
#define K2_STEP (K2_BLK * K2_THR)   // 524288 jobs per slab
#define K2_IT   (T4 / K2_STEP)      // 32 slabs

typedef float vfloat4 __attribute__((ext_vector_type(4)));

// K1: pool band+halo into LDS, 7x7 conv + bias + sigmoid -> att plane (4 MB ws).
// R12 post-mortem: traffic near-ideal but phase-serialized at 2 blocks/CU.
// BH=4 gives 1024 blocks (4/CU): pool-gather of one block overlaps conv/att of
// another. No phase-3 here; scaling moved to the pure-stream K2.
__global__ __launch_bounds__(256) void pool_conv_kernel(const float* __restrict__ x,
                                                        const float* __restrict__ cw,
                                                        const float* __restrict__ cb,
                                                        float* __restrict__ att) {
    __shared__ float sw[99];          // [0..48] avg taps, [49..97] max taps, [98] bias
    __shared__ float ap[PR][WW_];     // pooled avg rows (10 x 256 = 10 KiB)
    __shared__ float mp[PR][WW_];     // pooled max rows

    const int tid = threadIdx.x;
    if (tid < 99) sw[tid] = (tid < 98) ? cw[tid] : cb[0];

    const int bid  = blockIdx.x;
    const int b    = bid >> 6;                  // image index
    const int band = bid & (NBANDS - 1);        // band within image
    const int R0   = band * BH;                 // first output row

    const float4* xb4 = (const float4*)x + (size_t)b * (CHW / 4);

    // Phase 1: pool 10 halo'd rows. 640 jobs over 256 threads (2.5 sweeps).
    for (int j = tid; j < PR * 64; j += 256) {
        const int i   = j >> 6;                 // LDS row 0..9
        const int q   = j & 63;                 // col quad
        const int row = R0 - HALO + i;
        float4 a = {0.f, 0.f, 0.f, 0.f};        // out-of-image halo = 0 (zero pad)
        float4 m = {0.f, 0.f, 0.f, 0.f};
        if (row >= 0 && row < HH_) {
            const float4* p = xb4 + row * 64 + q;
            float4 s  = {0.f, 0.f, 0.f, 0.f};
            float4 mm = {-INFINITY, -INFINITY, -INFINITY, -INFINITY};
            #pragma unroll 16
            for (int c = 0; c < CC; ++c) {
                float4 v = p[c * (HW / 4)];
                s.x += v.x; s.y += v.y; s.z += v.z; s.w += v.w;
                mm.x = fmaxf(mm.x, v.x); mm.y = fmaxf(mm.y, v.y);
                mm.z = fmaxf(mm.z, v.z); mm.w = fmaxf(mm.w, v.w);
            }
            const float inv = 1.0f / 64.0f;
            a.x = s.x * inv; a.y = s.y * inv; a.z = s.z * inv; a.w = s.w * inv;
            m = mm;
        }
        *(float4*)&ap[i][q * 4] = a;
        *(float4*)&mp[i][q * 4] = m;
    }
    __syncthreads();

    // Phase 2: conv from LDS -> sigmoid -> att. One job per thread (4x64 = 256).
    const float bias = sw[98];
    const int rl  = tid >> 6;                   // band-local row 0..3
    const int q   = tid & 63;                   // col quad
    const int row = R0 + rl;

    float acc0 = bias, acc1 = bias, acc2 = bias, acc3 = bias;
    #pragma unroll
    for (int dy = -3; dy <= 3; ++dy) {
        const int li = rl + HALO + dy;          // LDS row, always in [0, PR)
        const float4* a4 = (const float4*)&ap[li][0];
        const float4* m4 = (const float4*)&mp[li][0];
        const float4 z = {0.f, 0.f, 0.f, 0.f};
        float4 aL = (q > 0)  ? a4[q - 1] : z;   // col zero-padding at image edge
        float4 aC = a4[q];
        float4 aR = (q < 63) ? a4[q + 1] : z;
        float4 mL = (q > 0)  ? m4[q - 1] : z;
        float4 mC = m4[q];
        float4 mR = (q < 63) ? m4[q + 1] : z;
        float av[12] = {aL.x,aL.y,aL.z,aL.w, aC.x,aC.y,aC.z,aC.w, aR.x,aR.y,aR.z,aR.w};
        float mv[12] = {mL.x,mL.y,mL.z,mL.w, mC.x,mC.y,mC.z,mC.w, mR.x,mR.y,mR.z,mR.w};
        const float* wr = sw + (dy + 3) * 7;
        #pragma unroll
        for (int kx = 0; kx < 7; ++kx) {
            float wa = wr[kx];
            float wm = wr[49 + kx];
            int t = 1 + kx;
            acc0 = fmaf(av[t + 0], wa, acc0);  acc0 = fmaf(mv[t + 0], wm, acc0);
            acc1 = fmaf(av[t + 1], wa, acc1);  acc1 = fmaf(mv[t + 1], wm, acc1);
            acc2 = fmaf(av[t + 2], wa, acc2);  acc2 = fmaf(mv[t + 2], wm, acc2);
            acc3 = fmaf(av[t + 3], wa, acc3);  acc3 = fmaf(mv[t + 3], wm, acc3);
        }
    }

    float4 attq;
    attq.x = 1.f / (1.f + __expf(-acc0));
    attq.y = 1.f / (1.f + __expf(-acc1));
    attq.z = 1.f / (1.f + __expf(-acc2));
    attq.w = 1.f / (1.f + __expf(-acc3));
    ((float4*)att)[b * (HW / 4) + row * 64 + q] = attq;   // cached store: re-read by K2
}

// K2: out = x * att. Pure grid-stride stream: no LDS, no barriers, ~32 waves/CU.
// Slabs walked in DESCENDING address order (+ reversed bid) to MRU-chase the L3
// that K1 just filled with x (forward sweep). NT on x/out keeps the write-once
// stream from evicting pending x lines; att (4 MB) stays L2/L3-resident.
__global__ __launch_bounds__(K2_THR) void scale_kernel(const float* __restrict__ x,
                                                       const float* __restrict__ att,
                                                       float* __restrict__ out) {
    const int rbid = gridDim.x - 1 - blockIdx.x;
    const int lane = rbid * K2_THR + threadIdx.x;        // [0, K2_STEP)
    const vfloat4* x4   = (const vfloat4*)x;
    const vfloat4* att4 = (const vfloat4*)att;
    vfloat4*       o4   = (vfloat4*)out;

    for (int s = K2_IT - 1; s >= 0; --s) {               // descending slabs
        const int j  = s * K2_STEP + lane;
        const int b  = j >> 20;                          // / (CHW/4)
        const int p4 = j & 16383;                        // pixel quad within plane
        vfloat4 v = __builtin_nontemporal_load(x4 + j);  // x dead after this
        vfloat4 a = att4[b * (HW / 4) + p4];             // cached: L2/L3-resident
        vfloat4 r;
        r.x = v.x * a.x; r.y = v.y * a.y; r.z = v.z * a.z; r.w = v.w * a.w;
        __builtin_nontemporal_store(r, o4 + j);          // out never re-read
    }
}

extern "C" void kernel_launch(void* const* d_in, const int* in_sizes, int n_in,
                              void* d_out, int out_size, void* d_ws, size_t ws_size,
                              hipStream_t stream) {
    const float* x  = (const float*)d_in[0];
    const float* cw = (const float*)d_in[1];   // [1,2,7,7] = 98 floats
    const float* cb = (const float*)d_in[2];   // [1]
    float* out = (float*)d_out;

    float* att = (float*)d_ws;                 // NPIX floats = 4 MB (ws held >=8 MB before)

    pool_conv_kernel<<<dim3(NBLK), dim3(256), 0, stream>>>(x, cw, cb, att);
    scale_kernel<<<dim3(K2_BLK), dim3(K2_THR), 0, stream>>>(x, att, out);
}

// Round 16
// 491.546 us; speedup vs baseline: 1.0751x; 1.0751x over previous
//
#include <hip/hip_runtime.h>
#include <math.h>

// Problem constants: x [B=16, C=64, H=256, W=256] fp32
#define BB   16
#define CC   64
#define HH_  256
#define WW_  256
#define HW   (HH_ * WW_)        // 65536
#define CHW  (CC * HW)          // 4194304
#define NPIX (BB * HW)          // 1048576
#define N4   (NPIX / 4)         // 262144 threads, 4 pixels each

// Native clang vector type for __builtin_nontemporal_load/store.
typedef float vfloat4 __attribute__((ext_vector_type(4)));

// Kernel 1: channel mean + channel max -> avg plane, max plane (each B*HW floats)
// Cached loads on purpose: this pass warms L3 (and per-XCD L2 tails) with x so
// kernel 2 can re-read it from cache.
__global__ __launch_bounds__(256) void pool_kernel(const float* __restrict__ x,
                                                   float* __restrict__ avgp,
                                                   float* __restrict__ maxp) {
    int idx = blockIdx.x * blockDim.x + threadIdx.x;   // [0, N4)
    int b  = idx >> 14;                                // / (HW/4)
    int p4 = idx & 16383;                              // float4 index within plane

    const float4* x4 = (const float4*)x + (size_t)b * (CHW / 4) + p4;

    float4 s = {0.f, 0.f, 0.f, 0.f};
    float4 m = {-INFINITY, -INFINITY, -INFINITY, -INFINITY};
    #pragma unroll 8
    for (int c = 0; c < CC; ++c) {
        float4 v = x4[c * (HW / 4)];
        s.x += v.x; s.y += v.y; s.z += v.z; s.w += v.w;
        m.x = fmaxf(m.x, v.x); m.y = fmaxf(m.y, v.y);
        m.z = fmaxf(m.z, v.z); m.w = fmaxf(m.w, v.w);
    }
    const float inv = 1.0f / 64.0f;
    float4 a = {s.x * inv, s.y * inv, s.z * inv, s.w * inv};
    ((float4*)avgp)[idx] = a;
    ((float4*)maxp)[idx] = m;
}

// Kernel 2: 7x7 conv (avg,max planes) + bias + sigmoid, then out = x * att.
// One thread = 4 consecutive pixels; one wave = one full 256-px row.
//
// Block order: XCD-PRESERVING descending map (refines R7's plain reversal).
// Round-robin dispatch puts block id d on XCD d%8; pool block `orig` warmed
// XCD orig%8's L2 with its x tail. Mapping d -> orig = (d&7) + 8*(127 - d>>3)
// keeps the same XCD lane AND walks it backwards: the freshest ~4 MiB per XCD
// upgrades from L3-hit to L2-hit, while globally chasing the L3 MRU frontier.
// NT x-loads/out-stores keep the 512 MiB write-once/dead stream from evicting
// pending x lines (NT loads also skip re-allocation on miss).
__global__ __launch_bounds__(256) void conv_scale_kernel(const float* __restrict__ x,
                                                         const float* __restrict__ avgp,
                                                         const float* __restrict__ maxp,
                                                         const float* __restrict__ cw,
                                                         const float* __restrict__ cb,
                                                         float* __restrict__ out) {
    __shared__ float sw[99];                 // [0..48] avg taps, [49..97] max taps, [98] bias
    if (threadIdx.x < 99)
        sw[threadIdx.x] = (threadIdx.x < 98) ? cw[threadIdx.x] : cb[0];
    __syncthreads();

    const int d = blockIdx.x;                // [0,1024)
    const int k = d & 7;                     // XCD lane (round-robin heuristic)
    const int m = d >> 3;                    // position within lane, [0,128)
    const int bid = k + ((127 - m) << 3);    // same XCD, descending: L2+L3 MRU chase

    int idx = bid * blockDim.x + threadIdx.x;           // [0, N4)
    int b   = idx >> 14;
    int p4  = idx & 16383;
    int pix = p4 << 2;                                  // pixel index in plane
    int h   = pix >> 8;                                 // row (wave-uniform)
    int q   = p4 & 63;                                  // w0/4  (w0 = q*4)

    const float* ap = avgp + b * HW;
    const float* mp = maxp + b * HW;

    float bias = sw[98];
    float acc0 = bias, acc1 = bias, acc2 = bias, acc3 = bias;

    for (int dy = -3; dy <= 3; ++dy) {
        int hh = h + dy;
        if (hh < 0 || hh >= HH_) continue;              // zero row padding
        const float4* a4 = (const float4*)(ap + hh * WW_);
        const float4* m4 = (const float4*)(mp + hh * WW_);
        const float4 z = {0.f, 0.f, 0.f, 0.f};
        // cols w0-4 .. w0+7 (12 values); col<0 / col>=W are zero padding
        float4 aL = (q > 0)  ? a4[q - 1] : z;
        float4 aC = a4[q];
        float4 aR = (q < 63) ? a4[q + 1] : z;
        float4 mL = (q > 0)  ? m4[q - 1] : z;
        float4 mC = m4[q];
        float4 mR = (q < 63) ? m4[q + 1] : z;
        float av[12] = {aL.x, aL.y, aL.z, aL.w, aC.x, aC.y, aC.z, aC.w, aR.x, aR.y, aR.z, aR.w};
        float mv[12] = {mL.x, mL.y, mL.z, mL.w, mC.x, mC.y, mC.z, mC.w, mR.x, mR.y, mR.z, mR.w};

        const float* wr = sw + (dy + 3) * 7;            // avg taps row; +49 for max taps
        #pragma unroll
        for (int kx = 0; kx < 7; ++kx) {
            float wa = wr[kx];
            float wm = wr[49 + kx];
            int t = 1 + kx;                              // av index = j + (kx-3) + 4
            acc0 = fmaf(av[t + 0], wa, acc0);  acc0 = fmaf(mv[t + 0], wm, acc0);
            acc1 = fmaf(av[t + 1], wa, acc1);  acc1 = fmaf(mv[t + 1], wm, acc1);
            acc2 = fmaf(av[t + 2], wa, acc2);  acc2 = fmaf(mv[t + 2], wm, acc2);
            acc3 = fmaf(av[t + 3], wa, acc3);  acc3 = fmaf(mv[t + 3], wm, acc3);
        }
    }

    float att0 = 1.f / (1.f + __expf(-acc0));
    float att1 = 1.f / (1.f + __expf(-acc1));
    float att2 = 1.f / (1.f + __expf(-acc2));
    float att3 = 1.f / (1.f + __expf(-acc3));

    const vfloat4* xb = (const vfloat4*)x + (size_t)b * (CHW / 4) + p4;
    vfloat4*       ob = (vfloat4*)out     + (size_t)b * (CHW / 4) + p4;
    #pragma unroll 4
    for (int c = 0; c < CC; ++c) {
        vfloat4 v = __builtin_nontemporal_load(xb + c * (HW / 4));  // x dead after this
        vfloat4 r;
        r.x = v.x * att0; r.y = v.y * att1; r.z = v.z * att2; r.w = v.w * att3;
        __builtin_nontemporal_store(r, ob + c * (HW / 4));          // out never re-read
    }
}

extern "C" void kernel_launch(void* const* d_in, const int* in_sizes, int n_in,
                              void* d_out, int out_size, void* d_ws, size_t ws_size,
                              hipStream_t stream) {
    const float* x  = (const float*)d_in[0];
    const float* cw = (const float*)d_in[1];   // [1,2,7,7] = 98 floats
    const float* cb = (const float*)d_in[2];   // [1]
    float* out = (float*)d_out;

    float* avgp = (float*)d_ws;                // B*HW floats
    float* maxp = avgp + NPIX;                 // B*HW floats

    dim3 block(256);
    dim3 grid(N4 / 256);                       // 1024 blocks
    pool_kernel<<<grid, block, 0, stream>>>(x, avgp, maxp);
    conv_scale_kernel<<<grid, block, 0, stream>>>(x, avgp, maxp, cw, cb, out);
}